// Round 1
// baseline (3563.257 us; speedup 1.0000x reference)
//
#include <hip/hip_runtime.h>

// MaskedConv2D: B=8, CIN=64, COUT=64, H=W=256, K=3, PAD=1, fp32.
// out[b,co,h,w] = valid[b,h,w] ? (sum_{ci,kh,kw} x[b,ci,h+kh-1,w+kw-1]*W[co,ci,kh,kw] + bias[co]) : 0
// valid = OR of mask over the 3x3 window (zero-padded).

#define B_   8
#define CIN_ 64
#define COUT_ 64
#define H_   256
#define W_   256
#define HW_  (H_ * W_)

// Block: 256 threads = 64 w-pixels x 4 co-groups (16 co each).
// Grid: (W/64, H, B). Each thread: 16 accumulators (one pixel, 16 channels).
__global__ __launch_bounds__(256) void masked_conv3x3(
    const float* __restrict__ x,
    const float* __restrict__ mask,
    const float* __restrict__ wgt,   // [COUT][CIN][3][3]
    const float* __restrict__ bias,  // [COUT]
    float* __restrict__ out)
{
    const int tid = threadIdx.x;
    const int w  = blockIdx.x * 64 + (tid & 63);
    const int h  = blockIdx.y;
    const int b  = blockIdx.z;
    const int co_base = (tid >> 6) * 16;

    // ---- validity: OR of mask over 3x3 window, zero padding ----
    const float* m = mask + b * HW_;
    bool valid = false;
    #pragma unroll
    for (int dh = -1; dh <= 1; ++dh) {
        const int hh = h + dh;
        if (hh < 0 || hh >= H_) continue;
        #pragma unroll
        for (int dw = -1; dw <= 1; ++dw) {
            const int ww = w + dw;
            if (ww < 0 || ww >= W_) continue;
            if (m[hh * W_ + ww] != 0.0f) valid = true;
        }
    }

    float acc[16];
    #pragma unroll
    for (int j = 0; j < 16; ++j) acc[j] = 0.0f;

    const float* xb = x + (size_t)b * CIN_ * HW_;
    const bool wm_ok = (w - 1) >= 0;
    const bool wp_ok = (w + 1) < W_;

    #pragma unroll 2
    for (int ci = 0; ci < CIN_; ++ci) {
        const float* xc = xb + ci * HW_;
        #pragma unroll
        for (int dh = 0; dh < 3; ++dh) {
            const int hh = h + dh - 1;
            const bool hin = (hh >= 0) && (hh < H_);
            const float* xr = xc + hh * W_;
            // 3-tap row of x (zero at padding)
            const float xm = (hin && wm_ok) ? xr[w - 1] : 0.0f;
            const float xz =  hin           ? xr[w]     : 0.0f;
            const float xp = (hin && wp_ok) ? xr[w + 1] : 0.0f;
            // weights: wave-uniform indices -> scalar loads + broadcast
            const float* wp_ = wgt + ((size_t)co_base * CIN_ + ci) * 9 + dh * 3;
            #pragma unroll
            for (int j = 0; j < 16; ++j) {
                const float* wj = wp_ + (size_t)j * CIN_ * 9;
                acc[j] = fmaf(wj[0], xm, acc[j]);
                acc[j] = fmaf(wj[1], xz, acc[j]);
                acc[j] = fmaf(wj[2], xp, acc[j]);
            }
        }
    }

    // ---- epilogue: bias + mask, write 16 channels ----
    float* ob = out + (size_t)b * COUT_ * HW_ + h * W_ + w;
    #pragma unroll
    for (int j = 0; j < 16; ++j) {
        const float v = valid ? (acc[j] + bias[co_base + j]) : 0.0f;
        ob[(size_t)(co_base + j) * HW_] = v;
    }
}

extern "C" void kernel_launch(void* const* d_in, const int* in_sizes, int n_in,
                              void* d_out, int out_size, void* d_ws, size_t ws_size,
                              hipStream_t stream) {
    const float* x    = (const float*)d_in[0];
    const float* mask = (const float*)d_in[1];
    const float* wgt  = (const float*)d_in[2];
    const float* bias = (const float*)d_in[3];
    float* out        = (float*)d_out;

    dim3 grid(W_ / 64, H_, B_);
    masked_conv3x3<<<grid, 256, 0, stream>>>(x, mask, wgt, bias, out);
}

// Round 2
// 407.841 us; speedup vs baseline: 8.7369x; 8.7369x over previous
//
#include <hip/hip_runtime.h>

// MaskedConv2D bf16-MFMA implicit GEMM. B=8, CIN=COUT=64, H=W=256, K=3, PAD=1.
// out[b,co,h,w] = valid ? conv(x,W)[b,co,h,w] + bias[co] : 0
// valid = OR of mask over 3x3 window.
//
// GEMM view: M=64 (co), K=576 (ci*9 taps), N=pixels.
// Block tile: 64 co x (4 rows x 64 cols). 4 waves; wave r handles output row r.
// mfma_f32_16x16x32_bf16: A[m=lane&15][k=(lane>>4)*8+j], B[k][n=lane&15],
// C/D: col=lane&15, row=(lane>>4)*4+reg.

#define B_    8
#define C_    64
#define H_    256
#define W_    256
#define HW_   (H_ * W_)

typedef __attribute__((ext_vector_type(8))) short bf16x8;
typedef __attribute__((ext_vector_type(4))) float f32x4;

__device__ __forceinline__ unsigned short f2bf(float f) {
    unsigned int u = __float_as_uint(f);
    u = (u + 0x7FFFu + ((u >> 16) & 1u)) >> 16;   // RNE
    return (unsigned short)u;
}

// ---- weight conversion: fp32 [co][ci][3][3] -> bf16 A-fragment blob ----
// blob layout: frag f = s*4 + mf  (s = tap*2 + kblk, 18 steps; mf = 0..3)
//   lane l holds 8 bf16 (16B) at byte offset (f*64 + l)*16:
//   co = mf*16 + (l&15); ci = kblk*32 + (l>>4)*8 + j
__global__ __launch_bounds__(256) void wconv(const float* __restrict__ wgt,
                                             unsigned short* __restrict__ wsA)
{
    const int gid  = blockIdx.x * 256 + threadIdx.x;   // 18*256 = 4608
    const int s    = gid >> 8;
    const int rest = gid & 255;
    const int mf   = rest >> 6;
    const int lane = rest & 63;
    const int tap  = s >> 1;
    const int kblk = s & 1;
    const int kh = tap / 3, kw = tap % 3;
    const int co = mf * 16 + (lane & 15);
    unsigned short v[8];
#pragma unroll
    for (int j = 0; j < 8; ++j) {
        const int ci = kblk * 32 + (lane >> 4) * 8 + j;
        v[j] = f2bf(wgt[((co * C_ + ci) * 3 + kh) * 3 + kw]);
    }
    unsigned short* dst = wsA + (size_t)gid * 8;
    *(uint4*)dst = *(const uint4*)v;
}

// ---- main kernel ----
// grid: (W/64, H/4, B); block 256 = 4 waves.
#define TROWS 6          // 4 + 2 halo
#define TCOLS 66         // 64 + 2 halo
#define CELLP 72         // padded ci stride (144 B: 16B-aligned, 2-way banks)

__global__ __launch_bounds__(256) void masked_conv_mfma(
    const float* __restrict__ x,
    const float* __restrict__ mask,
    const unsigned short* __restrict__ wsA,
    const float* __restrict__ bias,
    float* __restrict__ out)
{
    __shared__ unsigned short xs[TROWS * TCOLS * CELLP];  // 57024 B

    const int tid  = threadIdx.x;
    const int wave = tid >> 6;
    const int lane = tid & 63;
    const int l15  = lane & 15;
    const int lq   = lane >> 4;

    const int w0 = blockIdx.x * 64;
    const int h0 = blockIdx.y * 4;
    const int b  = blockIdx.z;

    // ---- stage x tile: [6 rows][66 cols][64 ci] bf16, ci packed in pairs ----
    const int NST = TROWS * 32 * TCOLS;   // 12672 pair-units
    for (int e = tid; e < NST; e += 256) {
        const int row = e / (32 * TCOLS);
        const int rem = e - row * (32 * TCOLS);
        const int ci2 = rem / TCOLS;
        const int col = rem - ci2 * TCOLS;
        const int gh = h0 - 1 + row;
        const int gw = w0 - 1 + col;
        float v0 = 0.0f, v1 = 0.0f;
        if (gh >= 0 && gh < H_ && gw >= 0 && gw < W_) {
            const float* px = x + ((size_t)(b * C_ + 2 * ci2) * H_ + gh) * W_ + gw;
            v0 = px[0];
            v1 = px[HW_];
        }
        const unsigned int packed = (unsigned int)f2bf(v0) | ((unsigned int)f2bf(v1) << 16);
        *(unsigned int*)&xs[(row * TCOLS + col) * CELLP + 2 * ci2] = packed;
    }
    __syncthreads();

    // ---- K loop: 9 taps x 2 ci-halves, no barriers ----
    f32x4 acc[4][4];
#pragma unroll
    for (int mf = 0; mf < 4; ++mf)
#pragma unroll
        for (int nf = 0; nf < 4; ++nf)
            acc[mf][nf] = (f32x4){0.f, 0.f, 0.f, 0.f};

    const bf16x8* wA = (const bf16x8*)wsA;

#pragma unroll 1
    for (int kh = 0; kh < 3; ++kh) {
        const int rowbase = (wave + kh) * TCOLS;
#pragma unroll
        for (int kw = 0; kw < 3; ++kw) {
#pragma unroll
            for (int kblk = 0; kblk < 2; ++kblk) {
                const int s = (kh * 3 + kw) * 2 + kblk;
                bf16x8 a[4];
#pragma unroll
                for (int mf = 0; mf < 4; ++mf)
                    a[mf] = wA[(s * 4 + mf) * 64 + lane];
                bf16x8 bf[4];
#pragma unroll
                for (int nf = 0; nf < 4; ++nf) {
                    const int cell = rowbase + nf * 16 + l15 + kw;
                    bf[nf] = *(const bf16x8*)&xs[cell * CELLP + kblk * 32 + lq * 8];
                }
#pragma unroll
                for (int mf = 0; mf < 4; ++mf)
#pragma unroll
                    for (int nf = 0; nf < 4; ++nf)
                        acc[mf][nf] = __builtin_amdgcn_mfma_f32_16x16x32_bf16(
                            a[mf], bf[nf], acc[mf][nf], 0, 0, 0);
            }
        }
    }

    // ---- validity: one pixel per lane (col = lane), broadcast via bpermute ----
    const int h = h0 + wave;
    const int wpx = w0 + lane;
    int valid = 0;
    const float* mb = mask + (size_t)b * HW_;
#pragma unroll
    for (int dh = -1; dh <= 1; ++dh) {
        const int hh = h + dh;
        if (hh < 0 || hh >= H_) continue;
#pragma unroll
        for (int dw = -1; dw <= 1; ++dw) {
            const int ww = wpx + dw;
            if (ww < 0 || ww >= W_) continue;
            if (mb[hh * W_ + ww] != 0.0f) valid = 1;
        }
    }

    // ---- epilogue: bias + mask select + store ----
#pragma unroll
    for (int nf = 0; nf < 4; ++nf) {
        const int c = nf * 16 + l15;
        const int vn = __builtin_amdgcn_ds_bpermute(c << 2, valid);
        float* ob = out + ((size_t)(b * C_) * H_ + h) * W_ + w0 + c;
#pragma unroll
        for (int mf = 0; mf < 4; ++mf) {
#pragma unroll
            for (int reg = 0; reg < 4; ++reg) {
                const int co = mf * 16 + lq * 4 + reg;
                const float val = vn ? (acc[mf][nf][reg] + bias[co]) : 0.0f;
                ob[(size_t)co * HW_] = val;
            }
        }
    }
}

extern "C" void kernel_launch(void* const* d_in, const int* in_sizes, int n_in,
                              void* d_out, int out_size, void* d_ws, size_t ws_size,
                              hipStream_t stream) {
    const float* x    = (const float*)d_in[0];
    const float* mask = (const float*)d_in[1];
    const float* wgt  = (const float*)d_in[2];
    const float* bias = (const float*)d_in[3];
    float* out        = (float*)d_out;
    unsigned short* wsA = (unsigned short*)d_ws;   // 73728 B used

    wconv<<<18, 256, 0, stream>>>(wgt, wsA);

    dim3 grid(W_ / 64, H_ / 4, B_);
    masked_conv_mfma<<<grid, 256, 0, stream>>>(x, mask, wsA, bias, out);
}

// Round 3
// 326.437 us; speedup vs baseline: 10.9156x; 1.2494x over previous
//
#include <hip/hip_runtime.h>

// MaskedConv2D bf16-MFMA implicit GEMM, v3. B=8, CIN=COUT=64, H=W=256, K=3, PAD=1.
// GEMM view: M=64 (co), K=576 (ci*9 taps), N=pixels.
// Block: 512 thr = 8 waves; tile = 64 co x (4 rows x 64 cols).
// Wave v: output row (v&3), col-half (v>>2) -> wave tile 64co x 32px, acc 4x2 frags.
// mfma_f32_16x16x32_bf16: A[m=lane&15][k=(lane>>4)*8+j], C/D: col=lane&15, row=(lane>>4)*4+reg.

#define B_    8
#define C_    64
#define H_    256
#define W_    256
#define HW_   (H_ * W_)

typedef __attribute__((ext_vector_type(8))) short bf16x8;
typedef __attribute__((ext_vector_type(4))) float f32x4;

__device__ __forceinline__ unsigned short f2bf(float f) {
    unsigned int u = __float_as_uint(f);
    u = (u + 0x7FFFu + ((u >> 16) & 1u)) >> 16;   // RNE
    return (unsigned short)u;
}

// ---- weight conversion: fp32 [co][ci][3][3] -> bf16 A-fragment blob ----
// frag f = s*4 + mf  (s = tap*2 + kblk); lane l holds 8 bf16 at (f*64+l)*16 B:
//   co = mf*16 + (l&15); ci = kblk*32 + (l>>4)*8 + j
__global__ __launch_bounds__(256) void wconv(const float* __restrict__ wgt,
                                             unsigned short* __restrict__ wsA)
{
    const int gid  = blockIdx.x * 256 + threadIdx.x;   // 18*256 = 4608
    const int s    = gid >> 8;
    const int rest = gid & 255;
    const int mf   = rest >> 6;
    const int lane = rest & 63;
    const int tap  = s >> 1;
    const int kblk = s & 1;
    const int kh = tap / 3, kw = tap % 3;
    const int co = mf * 16 + (lane & 15);
    unsigned short v[8];
#pragma unroll
    for (int j = 0; j < 8; ++j) {
        const int ci = kblk * 32 + (lane >> 4) * 8 + j;
        v[j] = f2bf(wgt[((co * C_ + ci) * 3 + kh) * 3 + kw]);
    }
    unsigned short* dst = wsA + (size_t)gid * 8;
    *(uint4*)dst = *(const uint4*)v;
}

// ---- main kernel ----
#define TROWS 6          // 4 + 2 halo
#define TCOLS 66         // 64 + 2 halo
#define CELLP 72         // padded ci stride in shorts (144 B; b128 reads/writes uniform)

__global__ __launch_bounds__(512, 4) void masked_conv_mfma(
    const float* __restrict__ x,
    const float* __restrict__ mask,
    const unsigned short* __restrict__ wsA,
    const float* __restrict__ bias,
    float* __restrict__ out)
{
    __shared__ unsigned short xs[TROWS * TCOLS * CELLP];  // 57024 B

    const int tid  = threadIdx.x;
    const int wave = tid >> 6;
    const int lane = tid & 63;
    const int l15  = lane & 15;
    const int lq   = lane >> 4;

    const int w0 = blockIdx.x * 64;
    const int h0 = blockIdx.y * 4;
    const int b  = blockIdx.z;

    // ---- stage x tile: [6 rows][66 cols][64 ci] bf16 ----
    // Work unit = (row, ci-octet, col): 8 strided global dwords -> 1 ds_write_b128.
    // Lanes vary col => global loads coalesced; LDS bank group = 4*(col%8), uniform.
    const int NU = TROWS * TCOLS * 8;   // 3168
    for (int u = tid; u < NU; u += 512) {
        const int col = u % TCOLS;
        const int t2  = u / TCOLS;
        const int oct = t2 & 7;
        const int row = t2 >> 3;
        const int gh = h0 - 1 + row;
        const int gw = w0 - 1 + col;
        unsigned short v[8];
        if (gh >= 0 && gh < H_ && gw >= 0 && gw < W_) {
            const float* px = x + ((size_t)(b * C_ + oct * 8) * H_ + gh) * W_ + gw;
#pragma unroll
            for (int j = 0; j < 8; ++j) v[j] = f2bf(px[(size_t)j * HW_]);
        } else {
#pragma unroll
            for (int j = 0; j < 8; ++j) v[j] = 0;
        }
        *(uint4*)&xs[((row * TCOLS) + col) * CELLP + oct * 8] = *(const uint4*)v;
    }
    __syncthreads();

    // ---- K loop: 9 taps x 2 ci-halves, no barriers ----
    const int hrow = wave & 3;        // output row within tile
    const int nh   = wave >> 2;       // col half (0/1)

    f32x4 acc[4][2];
#pragma unroll
    for (int mf = 0; mf < 4; ++mf)
#pragma unroll
        for (int nf = 0; nf < 2; ++nf)
            acc[mf][nf] = (f32x4){0.f, 0.f, 0.f, 0.f};

    const bf16x8* wA = (const bf16x8*)wsA;

#pragma unroll 1
    for (int kh = 0; kh < 3; ++kh) {
        const int rowbase = (hrow + kh) * TCOLS + nh * 32;
#pragma unroll
        for (int kw = 0; kw < 3; ++kw) {
#pragma unroll
            for (int kblk = 0; kblk < 2; ++kblk) {
                const int s = (kh * 3 + kw) * 2 + kblk;
                bf16x8 a[4];
#pragma unroll
                for (int mf = 0; mf < 4; ++mf)
                    a[mf] = wA[(s * 4 + mf) * 64 + lane];
                bf16x8 bf[2];
#pragma unroll
                for (int nf = 0; nf < 2; ++nf) {
                    const int cell = rowbase + nf * 16 + l15 + kw;
                    bf[nf] = *(const bf16x8*)&xs[cell * CELLP + kblk * 32 + lq * 8];
                }
#pragma unroll
                for (int mf = 0; mf < 4; ++mf)
#pragma unroll
                    for (int nf = 0; nf < 2; ++nf)
                        acc[mf][nf] = __builtin_amdgcn_mfma_f32_16x16x32_bf16(
                            a[mf], bf[nf], acc[mf][nf], 0, 0, 0);
            }
        }
    }

    // ---- validity: lanes 0..31 cover the wave's 32 px (lanes 32..63 duplicate) ----
    const int h = h0 + hrow;
    const int pcol = w0 + nh * 32 + (lane & 31);
    int valid = 0;
    const float* mb = mask + (size_t)b * HW_;
#pragma unroll
    for (int dh = -1; dh <= 1; ++dh) {
        const int hh = h + dh;
        if (hh < 0 || hh >= H_) continue;
#pragma unroll
        for (int dw = -1; dw <= 1; ++dw) {
            const int ww = pcol + dw;
            if (ww < 0 || ww >= W_) continue;
            if (mb[hh * W_ + ww] != 0.0f) valid = 1;
        }
    }

    // ---- epilogue: bias + mask select + store ----
#pragma unroll
    for (int nf = 0; nf < 2; ++nf) {
        const int cloc = nf * 16 + l15;                       // 0..31 within half
        const int vn = __builtin_amdgcn_ds_bpermute(cloc << 2, valid);
        float* ob = out + ((size_t)(b * C_) * H_ + h) * W_ + w0 + nh * 32 + cloc;
#pragma unroll
        for (int mf = 0; mf < 4; ++mf) {
#pragma unroll
            for (int reg = 0; reg < 4; ++reg) {
                const int co = mf * 16 + lq * 4 + reg;
                const float val = vn ? (acc[mf][nf][reg] + bias[co]) : 0.0f;
                ob[(size_t)co * HW_] = val;
            }
        }
    }
}

extern "C" void kernel_launch(void* const* d_in, const int* in_sizes, int n_in,
                              void* d_out, int out_size, void* d_ws, size_t ws_size,
                              hipStream_t stream) {
    const float* x    = (const float*)d_in[0];
    const float* mask = (const float*)d_in[1];
    const float* wgt  = (const float*)d_in[2];
    const float* bias = (const float*)d_in[3];
    float* out        = (float*)d_out;
    unsigned short* wsA = (unsigned short*)d_ws;   // 73728 B used

    wconv<<<18, 256, 0, stream>>>(wgt, wsA);

    dim3 grid(W_ / 64, H_ / 4, B_);
    masked_conv_mfma<<<grid, 512, 0, stream>>>(x, mask, wsA, bias, out);
}